// Round 8
// baseline (460.378 us; speedup 1.0000x reference)
//
#include <hip/hip_runtime.h>

typedef unsigned short u16;
typedef unsigned int   u32;
typedef __attribute__((ext_vector_type(8))) short bf8_t;   // 8 x bf16 (4 VGPRs)
typedef __attribute__((ext_vector_type(4))) float f4_t;    // 4 x fp32 acc

#define NB 256
#define NS 1024

__device__ __forceinline__ u16 f2bf(float f){   // RNE (used in prep only)
    u32 u = __float_as_uint(f);
    return (u16)((u + 0x7fffu + ((u >> 16) & 1u)) >> 16);
}
__device__ __forceinline__ u32 pack_trunc(float lo, float hi){  // 2 x fp32 -> packed bf16 (truncate)
    return (__float_as_uint(hi) & 0xffff0000u) | (__float_as_uint(lo) >> 16);
}

// ---- fused prep: blocks 0..511 -> per-(b,br) WeffT fragments + Cs (+y_trans);
//                  blocks 512..519 -> W (x-transform) B-fragment layout ----
__global__ __launch_bounds__(256) void prep_kernel(
    const float* __restrict__ y,    const float* __restrict__ wty,
    const float* __restrict__ bty,  const float* __restrict__ aty,
    const float* __restrict__ uid,  const float* __restrict__ ose, const float* __restrict__ zipc,
    const float* __restrict__ wlx,  const float* __restrict__ wnx,
    const float* __restrict__ lw1,  const float* __restrict__ lb1,
    const float* __restrict__ nw1,  const float* __restrict__ nb1,
    u32* __restrict__ wtf, u32* __restrict__ weff, float* __restrict__ cs)
{
    const int tid = threadIdx.x;
    const int bx  = blockIdx.x;

    if (bx >= 512) {
        // ---- wtf part: unit u = (br*16 + n*2 + ks)*64 + lane ----
        int u = (bx - 512)*256 + tid;   // 0..2047
        int lane = u & 63, fr = u >> 6;
        int br = fr >> 4, t = fr & 15, n = t >> 1, ks = t & 1;
        int q = lane >> 4, lm = lane & 15;
        const float* W = br ? wnx : wlx;
        u32 out[4];
        #pragma unroll
        for (int p = 0; p < 4; ++p) {
            int k = ks*32 + q*8 + p*2;
            float lo = W[k*128 + n*16 + lm];
            float hi = W[(k+1)*128 + n*16 + lm];
            out[p] = (u32)f2bf(lo) | ((u32)f2bf(hi) << 16);
        }
        *(uint4*)&wtf[u*4] = make_uint4(out[0], out[1], out[2], out[3]);
        return;
    }

    __shared__ float yl[64];
    __shared__ float sq[128];
    __shared__ float yv[128];
    __shared__ float cpart[240];

    const int b  = bx >> 1;
    const int br = bx & 1;
    const float* w1 = br ? nw1 : lw1;
    const float* b1 = br ? nb1 : lb1;

    // --- y_trans for this b ---
    if (tid < 64) yl[tid] = y[b*64 + tid];
    __syncthreads();
    float v = 0.f;
    if (tid < 128) {
        float acc = bty[tid];
        for (int k = 0; k < 64; ++k) acc = fmaf(yl[k], wty[k*128 + tid], acc);
        float a = aty[0];
        v = (acc >= 0.f) ? acc : a * acc;
        sq[tid] = v * v;
    }
    __syncthreads();
    for (int s = 64; s >= 1; s >>= 1) { if (tid < s) sq[tid] += sq[tid+s]; __syncthreads(); }
    if (tid < 128) yv[tid] = v * (1.f / fmaxf(sqrtf(sq[0]), 1e-12f));
    __syncthreads();

    // --- WeffT fragments: unit = fragrow*64+lane, fragrow = h*6+nj*2+ks ---
    for (int u = tid; u < 768; u += 256) {
        int lane = u & 63, fr = u >> 6;
        int h = fr / 6, t = fr % 6, nj = t >> 1, ks = t & 1;
        int q = lane >> 4, lm = lane & 15, j = nj*16 + lm;
        u32 out[4];
        #pragma unroll
        for (int p = 0; p < 4; ++p) {
            u32 w = 0;
            #pragma unroll
            for (int e = 0; e < 2; ++e) {
                int k = ks*32 + q*8 + p*2 + e;
                float val = 0.f;
                if (j < 40)
                    val = w1[k*40 + j] + w1[(128+k)*40 + j] + yv[h*64 + k] * w1[(64+k)*40 + j];
                w |= ((u32)f2bf(val)) << (16*e);
            }
            out[p] = w;
        }
        *(uint4*)&weff[((size_t)(br*NB + b)*12 + fr)*64*4 + lane*4] =
            make_uint4(out[0], out[1], out[2], out[3]);
    }

    // --- Cs partials: 240 threads, cj = h*40+j, slice of 120 terms ---
    if (tid < 240) {
        int cj = tid / 3, sl = tid % 3;
        int h = cj / 40, j = cj % 40;
        float acc = 0.f;
        for (int t = sl*40; t < sl*40 + 40; ++t) {
            if (t < 64) {
                acc = fmaf(yv[h*64 + t], w1[(192+t)*40 + j] - w1[(128+t)*40 + j], acc);
            } else {
                int u = t - 64;
                float sv, wv;
                if (u < 32)      { sv = uid[b*32 + u];        wv = w1[(256+u)*40 + j]; }
                else if (u < 40) { sv = ose[b*8 + (u-32)];    wv = w1[(288+(u-32))*40 + j]; }
                else             { sv = zipc[b*16 + (u-40)];  wv = w1[(296+(u-40))*40 + j]; }
                acc = fmaf(sv, wv, acc);
            }
        }
        cpart[tid] = acc;
    }
    __syncthreads();
    if (tid < 96) {
        int h = tid / 48, jj = tid % 48;
        float val = 0.f;
        if (jj < 40) {
            int cj = h*40 + jj;
            val = b1[jj] + cpart[cj*3] + cpart[cj*3+1] + cpart[cj*3+2];
        }
        cs[(size_t)(br*NB + b)*96 + tid] = val;
    }
}

// ---- main: one block per (b,br), 8 waves; wave w owns subtiles {w, w+8}; barrier-free loop ----
__global__ __launch_bounds__(512, 4) void main_kernel(
    const float* __restrict__ xloc, const float* __restrict__ xnon,
    const float* __restrict__ blx,  const float* __restrict__ alx,
    const float* __restrict__ bnx,  const float* __restrict__ anx,
    const float* __restrict__ la1,  const float* __restrict__ lw2, const float* __restrict__ lb2,
    const float* __restrict__ na1,  const float* __restrict__ nw2, const float* __restrict__ nb2,
    const u32* __restrict__ wtf, const u32* __restrict__ weff, const float* __restrict__ cs,
    float* __restrict__ out)
{
    __shared__ u16   tn[8*16*136];   // per-wave 16x128 bf16 tile, stride 136
    __shared__ float red[1024];

    const int tid  = threadIdx.x;
    const int b    = blockIdx.x;
    const int br   = blockIdx.y;
    const int w    = tid >> 6;      // 0..7
    const int lane = tid & 63;
    const int q    = lane >> 4;
    const int lm   = lane & 15;

    const float* xg   = br ? xnon : xloc;
    const float* bias = br ? bnx  : blx;
    const float  ax   = br ? anx[0] : alx[0];
    const float  a1v  = br ? na1[0] : la1[0];
    const float  b2v  = br ? nb2[0] : lb2[0];
    const float* w2   = br ? nw2  : lw2;

    // ---- fragment prologue (coalesced 16B loads, L2-hot) ----
    const bf8_t* wtfv  = (const bf8_t*)wtf;
    const bf8_t* weffv = (const bf8_t*)weff + (size_t)(br*NB + b)*12*64;
    bf8_t Bfrag[8][2];
    #pragma unroll
    for (int n = 0; n < 8; ++n)
        #pragma unroll
        for (int ks = 0; ks < 2; ++ks)
            Bfrag[n][ks] = wtfv[(br*16 + n*2 + ks)*64 + lane];
    bf8_t Cfrag[2][3][2];
    #pragma unroll
    for (int h = 0; h < 2; ++h)
        #pragma unroll
        for (int nj = 0; nj < 3; ++nj)
            #pragma unroll
            for (int ks = 0; ks < 2; ++ks)
                Cfrag[h][nj][ks] = weffv[(h*6 + nj*2 + ks)*64 + lane];

    float bv[8];
    #pragma unroll
    for (int n = 0; n < 8; ++n) bv[n] = bias[n*16 + lm];
    float w2v[3];
    #pragma unroll
    for (int nj = 0; nj < 3; ++nj) w2v[nj] = (nj*16 + lm < 40) ? w2[nj*16 + lm] : 0.f;
    float Cv[2][3];
    #pragma unroll
    for (int h = 0; h < 2; ++h)
        #pragma unroll
        for (int nj = 0; nj < 3; ++nj)
            Cv[h][nj] = cs[(size_t)(br*NB + b)*96 + h*48 + nj*16 + lm];

    u16* tw = &tn[w*2176];
    float outp[8];
    #pragma unroll
    for (int n = 0; n < 8; ++n) outp[n] = 0.f;

    const float* xb = &xg[(size_t)b*NS*64];
    // it = 0..7: subtile = w + (it>>2)*8, row-group = it&3
    #define ROWPTR(it) (xb + (size_t)(((w + (((it)>>2)*8))*64) + ((it)&3)*16 + lm)*64)

    float4 p0, p1, p2, p3;
    {
        const float* xr = ROWPTR(0);
        p0 = *(const float4*)(xr + q*8);
        p1 = *(const float4*)(xr + q*8 + 4);
        p2 = *(const float4*)(xr + 32 + q*8);
        p3 = *(const float4*)(xr + 32 + q*8 + 4);
    }

    #pragma unroll
    for (int it = 0; it < 8; ++it) {
        float4 c0 = p0, c1 = p1, c2 = p2, c3 = p3;
        if (it < 7) {
            const float* xr = ROWPTR(it + 1);
            p0 = *(const float4*)(xr + q*8);
            p1 = *(const float4*)(xr + q*8 + 4);
            p2 = *(const float4*)(xr + 32 + q*8);
            p3 = *(const float4*)(xr + 32 + q*8 + 4);
        }
        union { u32 u[4]; bf8_t v; } A0, A1;
        A0.u[0] = pack_trunc(c0.x, c0.y); A0.u[1] = pack_trunc(c0.z, c0.w);
        A0.u[2] = pack_trunc(c1.x, c1.y); A0.u[3] = pack_trunc(c1.z, c1.w);
        A1.u[0] = pack_trunc(c2.x, c2.y); A1.u[1] = pack_trunc(c2.z, c2.w);
        A1.u[2] = pack_trunc(c3.x, c3.y); A1.u[3] = pack_trunc(c3.z, c3.w);

        // ---- Phase B: t = prelu(x @ W + bias), 16 rows (bias folded into acc init) ----
        float tv[8][4];
        float ssq[4] = {0.f, 0.f, 0.f, 0.f};
        #pragma unroll
        for (int n = 0; n < 8; ++n) {
            f4_t acc = {bv[n], bv[n], bv[n], bv[n]};
            acc = __builtin_amdgcn_mfma_f32_16x16x32_bf16(A0.v, Bfrag[n][0], acc, 0, 0, 0);
            acc = __builtin_amdgcn_mfma_f32_16x16x32_bf16(A1.v, Bfrag[n][1], acc, 0, 0, 0);
            #pragma unroll
            for (int r = 0; r < 4; ++r) {
                float vv = acc[r];
                vv = (vv >= 0.f) ? vv : ax * vv;
                tv[n][r] = vv;
                ssq[r] = fmaf(vv, vv, ssq[r]);
            }
        }
        #pragma unroll
        for (int r = 0; r < 4; ++r) {
            float s = ssq[r];
            s += __shfl_xor(s, 1);
            s += __shfl_xor(s, 2);
            s += __shfl_xor(s, 4);
            s += __shfl_xor(s, 8);
            float rinv = rsqrtf(fmaxf(s, 1e-24f));   // == 1/max(sqrt(s),1e-12) for s>=1e-24
            #pragma unroll
            for (int n = 0; n < 8; ++n) tv[n][r] *= rinv;
        }
        // tn (bf16, truncate) -> wave-private LDS for C/D->A layout transform
        #pragma unroll
        for (int n = 0; n < 8; ++n)
            #pragma unroll
            for (int r = 0; r < 4; ++r)
                tw[(q*4+r)*136 + n*16 + lm] = (u16)(__float_as_uint(tv[n][r]) >> 16);

        // ---- Phase C: h1 = prelu(tn_h @ Weff + C); p = h1 @ w2 + b2 (C folded into acc) ----
        float pv[2][4];
        #pragma unroll
        for (int h = 0; h < 2; ++h) {
            bf8_t ac0 = *(const bf8_t*)&tw[lm*136 + h*64 + q*8];
            bf8_t ac1 = *(const bf8_t*)&tw[lm*136 + h*64 + 32 + q*8];
            float pp[4] = {0.f, 0.f, 0.f, 0.f};
            #pragma unroll
            for (int nj = 0; nj < 3; ++nj) {
                f4_t acc = {Cv[h][nj], Cv[h][nj], Cv[h][nj], Cv[h][nj]};
                acc = __builtin_amdgcn_mfma_f32_16x16x32_bf16(ac0, Cfrag[h][nj][0], acc, 0, 0, 0);
                acc = __builtin_amdgcn_mfma_f32_16x16x32_bf16(ac1, Cfrag[h][nj][1], acc, 0, 0, 0);
                #pragma unroll
                for (int r = 0; r < 4; ++r) {
                    float vv = acc[r];
                    vv = (vv >= 0.f) ? vv : a1v * vv;
                    pp[r] = fmaf(vv, w2v[nj], pp[r]);
                }
            }
            #pragma unroll
            for (int r = 0; r < 4; ++r) {
                float s = pp[r];
                s += __shfl_xor(s, 1);
                s += __shfl_xor(s, 2);
                s += __shfl_xor(s, 4);
                s += __shfl_xor(s, 8);
                pv[h][r] = s + b2v;
            }
        }

        // ---- Phase D (registers): out[col] += tn[row][col] * p[head][row] ----
        #pragma unroll
        for (int n = 0; n < 8; ++n)
            #pragma unroll
            for (int r = 0; r < 4; ++r)
                outp[n] = fmaf(tv[n][r], pv[n >> 2][r], outp[n]);
    }
    #undef ROWPTR

    // reduce quads within wave, combine 8 waves via LDS, direct store (covers all of out)
    #pragma unroll
    for (int n = 0; n < 8; ++n) {
        float vv = outp[n];
        vv += __shfl_xor(vv, 16);
        vv += __shfl_xor(vv, 32);
        outp[n] = vv;
    }
    if (lane < 16) {
        #pragma unroll
        for (int n = 0; n < 8; ++n) red[w*128 + n*16 + lane] = outp[n];
    }
    __syncthreads();
    if (tid < 128) {
        float s = 0.f;
        #pragma unroll
        for (int ww = 0; ww < 8; ++ww) s += red[ww*128 + tid];
        out[((size_t)br*NB + b)*128 + tid] = s;
    }
}

extern "C" void kernel_launch(void* const* d_in, const int* in_sizes, int n_in,
                              void* d_out, int out_size, void* d_ws, size_t ws_size,
                              hipStream_t stream)
{
    const float* xl  = (const float*)d_in[0];
    const float* xn  = (const float*)d_in[1];
    const float* y   = (const float*)d_in[2];
    const float* uid = (const float*)d_in[3];
    const float* ose = (const float*)d_in[4];
    const float* zp  = (const float*)d_in[5];
    const float* wty = (const float*)d_in[6];
    const float* bty = (const float*)d_in[7];
    const float* aty = (const float*)d_in[8];
    const float* wlx = (const float*)d_in[9];
    const float* blx = (const float*)d_in[10];
    const float* alx = (const float*)d_in[11];
    const float* wnx = (const float*)d_in[12];
    const float* bnx = (const float*)d_in[13];
    const float* anx = (const float*)d_in[14];
    const float* lw1 = (const float*)d_in[15];
    const float* lb1 = (const float*)d_in[16];
    const float* la1 = (const float*)d_in[17];
    const float* lw2 = (const float*)d_in[18];
    const float* lb2 = (const float*)d_in[19];
    const float* nw1 = (const float*)d_in[20];
    const float* nb1 = (const float*)d_in[21];
    const float* na1 = (const float*)d_in[22];
    const float* nw2 = (const float*)d_in[23];
    const float* nb2 = (const float*)d_in[24];

    // ws layout (16B-aligned segments)
    u32*   wtf  = (u32*)d_ws;                               // 2048*16B = 32 KB
    u32*   weff = (u32*)((char*)d_ws + 32768);              // 512*12*64*16B = 6 MB
    float* cs   = (float*)((char*)d_ws + 32768 + 6291456);  // 512*96*4 = 192 KB

    prep_kernel<<<dim3(520), dim3(256), 0, stream>>>(
        y, wty, bty, aty, uid, ose, zp, wlx, wnx, lw1, lb1, nw1, nb1, wtf, weff, cs);
    main_kernel<<<dim3(NB, 2), dim3(512), 0, stream>>>(
        xl, xn, blx, alx, bnx, anx,
        la1, lw2, lb2, na1, nw2, nb2,
        wtf, weff, cs, (float*)d_out);
}